// Round 7
// baseline (138.769 us; speedup 1.0000x reference)
//
#include <hip/hip_runtime.h>

#define N_NODES 20000
#define N_EDGES 640000
#define HIDDEN  128
#define CAP     96        // max in-degree; Binomial(640K,1/20K) tail @96 ~ e^-45
#define DEG_PAD 16        // one counter per 64B line

typedef unsigned short bf16_t;
typedef __attribute__((ext_vector_type(8))) short short8;            // 8 bf16
typedef __attribute__((ext_vector_type(4))) float floatx4;            // MFMA C/D

__device__ __forceinline__ bf16_t f2bf(float f) {
    union { float f; unsigned int i; } v; v.f = f;
    unsigned int x = v.i + 0x7FFFu + ((v.i >> 16) & 1u);   // RNE
    return (bf16_t)(x >> 16);
}
__device__ __forceinline__ float bflo(unsigned u) {
    union { unsigned i; float f; } v; v.i = u << 16; return v.f;
}
__device__ __forceinline__ float bfhi(unsigned u) {
    union { unsigned i; float f; } v; v.i = u & 0xFFFF0000u; return v.f;
}

// --- k1: feat fp32->bf16  +  bucket fill  +  Bp weight pack ---------------
// (R2-verified form.) Bp t = ((kt*8 + nt)*64 + lane)*8 + j holds B[k][n]:
//   k = kt*32 + (lane>>4)*8 + j   (K = 256: k<128 -> W_l (agg), k>=128 -> W_r (feat))
//   n = nt*16 + (lane&15)         (N = 128, output dim)
__global__ __launch_bounds__(256) void prep_fill_kernel(
        const float* __restrict__ feat,
        const float* __restrict__ Wl,
        const float* __restrict__ Wr,
        const int* __restrict__ eidx,
        bf16_t* __restrict__ feat_bf,
        bf16_t* __restrict__ Bp,
        int* __restrict__ deg,                 // pre-zeroed, stride DEG_PAD
        unsigned short* __restrict__ bucket) {
    int t = blockIdx.x * 256 + threadIdx.x;    // 0 .. 639999 exactly
    // feat convert: 640000 float4s
    float4 v = ((const float4*)feat)[t];
    ushort4 o = { f2bf(v.x), f2bf(v.y), f2bf(v.z), f2bf(v.w) };
    ((ushort4*)feat_bf)[t] = o;
    // edge fill: one atomic slot-claim per edge
    int src = eidx[t];
    int dst = eidx[N_EDGES + t];
    int pos = atomicAdd(&deg[dst * DEG_PAD], 1);
    if (pos < CAP) bucket[dst * CAP + pos] = (unsigned short)src;
    // Bp pack: 32768 entries (K=256 x N=128)
    if (t < 2 * HIDDEN * HIDDEN) {
        int j    = t & 7;
        int lane = (t >> 3) & 63;
        int nt   = (t >> 9) & 7;
        int kt   = t >> 12;
        int n = nt * 16 + (lane & 15);
        int k = kt * 32 + (lane >> 4) * 8 + j;
        float w = (k < HIDDEN) ? Wl[n * HIDDEN + k] : Wr[n * HIDDEN + (k - HIDDEN)];
        Bp[t] = f2bf(w);
    }
}

// --- k2: half-row split-pass agg, 8 row-halves per load instruction --------
// Pass h gathers only the 128B half [h*128, h*128+128) of each neighbor row.
// Lane (g = lane>>3, c = lane&7): group g owns neighbor-row k+g, lane loads
// 16B (uint4) at feat_bf[idx*256B + h*128B + c*16B]. One instruction = 8
// row-halves = 8 lines -> total VMEM instr count UNCHANGED vs R6 (160K),
// but per-pass working set = 20000 x 128B = 2.56 MB -> fits a 4 MiB XCD-L2
// (full 5.1 MB table does not). Dispatch boundary separates the passes.
// Cross-group reduce: shfl_xor 8/16/32 on the 8 per-lane column sums.
__global__ __launch_bounds__(256) void agg_half_kernel(
        const bf16_t* __restrict__ feat_bf,
        const int* __restrict__ deg,
        const unsigned short* __restrict__ bucket,
        bf16_t* __restrict__ agg,
        int half) {
    int wid  = (blockIdx.x * 256 + threadIdx.x) >> 6;
    int lane = threadIdx.x & 63;
    if (wid >= N_NODES) return;
    int g = lane >> 3;         // neighbor-row group (0..7)
    int c = lane & 7;          // 16B chunk within the half-row (0..7)
    int d_true = deg[wid * DEG_PAD];
    int d = min(d_true, CAP);
    const unsigned short* row = bucket + (size_t)wid * CAP;   // 192B stride
    const uint4* yq = (const uint4*)feat_bf;   // row idx -> 16 uint4 chunks
    int hc = half * 8 + c;                     // chunk index within full row

    float a0=0,a1=0,a2=0,a3=0,a4=0,a5=0,a6=0,a7=0;
    int k = 0;
    for (; k + 32 <= d; k += 32) {            // 32 rows / 4 loads in flight
        int i0 = (int)row[k      + g];
        int i1 = (int)row[k + 8  + g];
        int i2 = (int)row[k + 16 + g];
        int i3 = (int)row[k + 24 + g];
        uint4 u0 = yq[i0 * 16 + hc];
        uint4 u1 = yq[i1 * 16 + hc];
        uint4 u2 = yq[i2 * 16 + hc];
        uint4 u3 = yq[i3 * 16 + hc];
        a0 += bflo(u0.x); a1 += bfhi(u0.x); a2 += bflo(u0.y); a3 += bfhi(u0.y);
        a4 += bflo(u0.z); a5 += bfhi(u0.z); a6 += bflo(u0.w); a7 += bfhi(u0.w);
        a0 += bflo(u1.x); a1 += bfhi(u1.x); a2 += bflo(u1.y); a3 += bfhi(u1.y);
        a4 += bflo(u1.z); a5 += bfhi(u1.z); a6 += bflo(u1.w); a7 += bfhi(u1.w);
        a0 += bflo(u2.x); a1 += bfhi(u2.x); a2 += bflo(u2.y); a3 += bfhi(u2.y);
        a4 += bflo(u2.z); a5 += bfhi(u2.z); a6 += bflo(u2.w); a7 += bfhi(u2.w);
        a0 += bflo(u3.x); a1 += bfhi(u3.x); a2 += bflo(u3.y); a3 += bfhi(u3.y);
        a4 += bflo(u3.z); a5 += bfhi(u3.z); a6 += bflo(u3.w); a7 += bfhi(u3.w);
    }
    for (; k + 16 <= d; k += 16) {            // 16 rows / 2 loads
        int i0 = (int)row[k     + g];
        int i1 = (int)row[k + 8 + g];
        uint4 u0 = yq[i0 * 16 + hc];
        uint4 u1 = yq[i1 * 16 + hc];
        a0 += bflo(u0.x); a1 += bfhi(u0.x); a2 += bflo(u0.y); a3 += bfhi(u0.y);
        a4 += bflo(u0.z); a5 += bfhi(u0.z); a6 += bflo(u0.w); a7 += bfhi(u0.w);
        a0 += bflo(u1.x); a1 += bfhi(u1.x); a2 += bflo(u1.y); a3 += bfhi(u1.y);
        a4 += bflo(u1.z); a5 += bfhi(u1.z); a6 += bflo(u1.w); a7 += bfhi(u1.w);
    }
    for (; k < d; k += 8) {                   // predicated 8-row tail
        int kk = k + g;
        int ia = (int)row[kk < d ? kk : (d - 1)];
        uint4 u = yq[ia * 16 + hc];
        if (kk >= d) { u.x = 0u; u.y = 0u; u.z = 0u; u.w = 0u; }
        a0 += bflo(u.x); a1 += bfhi(u.x); a2 += bflo(u.y); a3 += bfhi(u.y);
        a4 += bflo(u.z); a5 += bfhi(u.z); a6 += bflo(u.w); a7 += bfhi(u.w);
    }
    // butterfly over the 8 groups (same c, g ^= 1,2,4 <-> lane ^= 8,16,32)
    a0 += __shfl_xor(a0, 8);  a1 += __shfl_xor(a1, 8);
    a2 += __shfl_xor(a2, 8);  a3 += __shfl_xor(a3, 8);
    a4 += __shfl_xor(a4, 8);  a5 += __shfl_xor(a5, 8);
    a6 += __shfl_xor(a6, 8);  a7 += __shfl_xor(a7, 8);
    a0 += __shfl_xor(a0, 16); a1 += __shfl_xor(a1, 16);
    a2 += __shfl_xor(a2, 16); a3 += __shfl_xor(a3, 16);
    a4 += __shfl_xor(a4, 16); a5 += __shfl_xor(a5, 16);
    a6 += __shfl_xor(a6, 16); a7 += __shfl_xor(a7, 16);
    a0 += __shfl_xor(a0, 32); a1 += __shfl_xor(a1, 32);
    a2 += __shfl_xor(a2, 32); a3 += __shfl_xor(a3, 32);
    a4 += __shfl_xor(a4, 32); a5 += __shfl_xor(a5, 32);
    a6 += __shfl_xor(a6, 32); a7 += __shfl_xor(a7, 32);
    if (g == 0) {
        float inv = 1.0f / fmaxf((float)d_true, 1.0f);
        uint4 o;
        o.x = (unsigned)f2bf(a0 * inv) | ((unsigned)f2bf(a1 * inv) << 16);
        o.y = (unsigned)f2bf(a2 * inv) | ((unsigned)f2bf(a3 * inv) << 16);
        o.z = (unsigned)f2bf(a4 * inv) | ((unsigned)f2bf(a5 * inv) << 16);
        o.w = (unsigned)f2bf(a6 * inv) | ((unsigned)f2bf(a7 * inv) << 16);
        ((uint4*)agg)[wid * 16 + hc] = o;
    }
}

// --- k3: MFMA GEMM  out = [agg | feat] @ [W_l ; W_r]^T + b  (fp32 out) -----
// (R2-verified form.) A-frag: lane holds A[m=lane&15][k=kt*32+(lane>>4)*8+j];
// kt<4 from agg, kt>=4 from feat_bf. C/D: col=lane&15, row=(lane>>4)*4+r
__global__ __launch_bounds__(256) void gemm_out_kernel(
        const bf16_t* __restrict__ agg,
        const bf16_t* __restrict__ feat_bf,
        const bf16_t* __restrict__ Bp,
        const float* __restrict__ bl,
        float* __restrict__ out) {
    int wid = blockIdx.x * 4 + (threadIdx.x >> 6);   // 16-row M-tile
    if (wid >= N_NODES / 16) return;
    int lane = threadIdx.x & 63;
    int m    = lane & 15;
    int quad = lane >> 4;
    int row0 = wid * 16;

    floatx4 acc[8];
    floatx4 zf = {0.f, 0.f, 0.f, 0.f};
#pragma unroll
    for (int nt = 0; nt < 8; ++nt) acc[nt] = zf;

    const short8* bp = (const short8*)Bp;
#pragma unroll
    for (int kt = 0; kt < 8; ++kt) {
        const bf16_t* abase = (kt < 4)
            ? (agg     + (size_t)(row0 + m) * HIDDEN + kt * 32 + quad * 8)
            : (feat_bf + (size_t)(row0 + m) * HIDDEN + (kt - 4) * 32 + quad * 8);
        short8 afrag = *(const short8*)abase;
#pragma unroll
        for (int nt = 0; nt < 8; ++nt) {
            short8 bfrag = bp[(kt * 8 + nt) * 64 + lane];
            acc[nt] = __builtin_amdgcn_mfma_f32_16x16x32_bf16(afrag, bfrag, acc[nt], 0, 0, 0);
        }
    }
    int col = lane & 15;
#pragma unroll
    for (int nt = 0; nt < 8; ++nt) {
        float b = bl[nt * 16 + col];
#pragma unroll
        for (int r = 0; r < 4; ++r) {
            int row = row0 + quad * 4 + r;
            out[(size_t)row * HIDDEN + nt * 16 + col] = acc[nt][r] + b;
        }
    }
}

extern "C" void kernel_launch(void* const* d_in, const int* in_sizes, int n_in,
                              void* d_out, int out_size, void* d_ws, size_t ws_size,
                              hipStream_t stream) {
    const float* feat = (const float*)d_in[0];
    const int*   eidx = (const int*)d_in[1];
    const float* Wl   = (const float*)d_in[2];
    const float* bl   = (const float*)d_in[3];
    const float* Wr   = (const float*)d_in[4];
    float* out = (float*)d_out;

    // workspace layout (~15 MB; ws is 256 MiB); all sections 16B-aligned
    int*            deg     = (int*)d_ws;                                   // 20000*16 int
    unsigned short* bucket  = (unsigned short*)(deg + N_NODES * DEG_PAD);   // 20000*96 u16
    bf16_t*         Bp      = (bf16_t*)(bucket + (size_t)N_NODES * CAP);    // 32768 bf16
    bf16_t*         feat_bf = Bp + 2 * HIDDEN * HIDDEN;                     // 20000*128 bf16
    bf16_t*         agg     = feat_bf + (size_t)N_NODES * HIDDEN;           // 20000*128 bf16

    hipMemsetAsync(deg, 0, (size_t)N_NODES * DEG_PAD * sizeof(int), stream);

    prep_fill_kernel<<<N_EDGES / 256, 256, 0, stream>>>(
        feat, Wl, Wr, eidx, feat_bf, Bp, deg, bucket);
    agg_half_kernel<<<(N_NODES * 64) / 256, 256, 0, stream>>>(
        feat_bf, deg, bucket, agg, 0);
    agg_half_kernel<<<(N_NODES * 64) / 256, 256, 0, stream>>>(
        feat_bf, deg, bucket, agg, 1);
    gemm_out_kernel<<<(N_NODES / 16 + 3) / 4, 256, 0, stream>>>(
        agg, feat_bf, Bp, bl, out);
}

// Round 10
// 138.095 us; speedup vs baseline: 1.0049x; 1.0049x over previous
//
#include <hip/hip_runtime.h>

#define N_NODES 20000
#define N_EDGES 640000
#define HIDDEN  128
#define CAP     96        // max in-degree; Binomial(640K,1/20K) tail @96 ~ e^-45
#define DEG_PAD 16        // one counter per 64B line

typedef unsigned short bf16_t;
typedef __attribute__((ext_vector_type(8))) short short8;            // 8 bf16
typedef __attribute__((ext_vector_type(4))) float floatx4;            // MFMA C/D
typedef float float2v __attribute__((ext_vector_type(2)));

__device__ __forceinline__ bf16_t f2bf(float f) {
    union { float f; unsigned int i; } v; v.f = f;
    unsigned int x = v.i + 0x7FFFu + ((v.i >> 16) & 1u);   // RNE
    return (bf16_t)(x >> 16);
}
__device__ __forceinline__ float bflo(unsigned u) {
    union { unsigned i; float f; } v; v.i = u << 16; return v.f;
}
__device__ __forceinline__ float bfhi(unsigned u) {
    union { unsigned i; float f; } v; v.i = u & 0xFFFF0000u; return v.f;
}
// float -> OCP e4m3fn, RNE, FTZ subnormals (values |f|<2^-6 -> 0; fine at our scale)
__device__ __forceinline__ unsigned f2fp8(float f) {
    union { float f; unsigned u; } v; v.f = f;
    unsigned s = (v.u >> 24) & 0x80u;
    unsigned a = v.u & 0x7FFFFFFFu;
    if (a > 0x43E00000u) a = 0x43E00000u;        // clamp to 448 (unreachable for N(0,1))
    a = a + 0x0007FFFFu + ((a >> 20) & 1u);      // RNE at 3-bit mantissa
    int e = (int)(a >> 23) - 120;
    unsigned m = (a >> 20) & 7u;
    unsigned em = (e <= 0) ? 0u : (((unsigned)e << 3) | m);
    if (e > 15) em = 0x7Eu;                      // clamp (unreachable)
    return s | em;
}
// 2x fp8(e4m3) -> 2x f32 from a dword; HI selects bytes 2,3. HW convert on
// gfx950; the builtin's word-select must be a LITERAL constant -> template.
template <bool HI>
__device__ __forceinline__ float2v fp8pair(unsigned w) {
#if defined(__has_builtin) && __has_builtin(__builtin_amdgcn_cvt_pk_f32_fp8)
    return __builtin_amdgcn_cvt_pk_f32_fp8(w, HI);
#else
    unsigned p = HI ? (w >> 16) : (w & 0xFFFFu);
    float2v r;
    {   unsigned b = p & 0xFFu, ss = (b & 0x80u) << 24, em = b & 0x7Fu;
        union { unsigned u; float f; } t; t.u = ss | ((em << 20) + 0x3C000000u);
        r.x = em ? t.f : 0.0f; }
    {   unsigned b = (p >> 8) & 0xFFu, ss = (b & 0x80u) << 24, em = b & 0x7Fu;
        union { unsigned u; float f; } t; t.u = ss | ((em << 20) + 0x3C000000u);
        r.y = em ? t.f : 0.0f; }
    return r;
#endif
}

// --- k1: feat fp32 -> {bf16 (GEMM), fp8 (gather table)} + bucket + Bp ------
// (R2-verified skeleton + fp8 table write.)
__global__ __launch_bounds__(256) void prep_fill_kernel(
        const float* __restrict__ feat,
        const float* __restrict__ Wl,
        const float* __restrict__ Wr,
        const int* __restrict__ eidx,
        bf16_t* __restrict__ feat_bf,
        unsigned char* __restrict__ feat_f8,
        bf16_t* __restrict__ Bp,
        int* __restrict__ deg,                 // pre-zeroed, stride DEG_PAD
        unsigned short* __restrict__ bucket) {
    int t = blockIdx.x * 256 + threadIdx.x;    // 0 .. 639999 exactly
    // feat convert: 640000 float4s -> bf16x4 and fp8x4
    float4 v = ((const float4*)feat)[t];
    ushort4 o = { f2bf(v.x), f2bf(v.y), f2bf(v.z), f2bf(v.w) };
    ((ushort4*)feat_bf)[t] = o;
    unsigned q = f2fp8(v.x) | (f2fp8(v.y) << 8) | (f2fp8(v.z) << 16) | (f2fp8(v.w) << 24);
    ((unsigned*)feat_f8)[t] = q;
    // edge fill: one atomic slot-claim per edge
    int src = eidx[t];
    int dst = eidx[N_EDGES + t];
    int pos = atomicAdd(&deg[dst * DEG_PAD], 1);
    if (pos < CAP) bucket[dst * CAP + pos] = (unsigned short)src;
    // Bp pack: 32768 entries (K=256 x N=128)
    if (t < 2 * HIDDEN * HIDDEN) {
        int j    = t & 7;
        int lane = (t >> 3) & 63;
        int nt   = (t >> 9) & 7;
        int kt   = t >> 12;
        int n = nt * 16 + (lane & 15);
        int k = kt * 32 + (lane >> 4) * 8 + j;
        float w = (k < HIDDEN) ? Wl[n * HIDDEN + k] : Wr[n * HIDDEN + (k - HIDDEN)];
        Bp[t] = f2bf(w);
    }
}

// --- k2: agg[i] = mean_{j in N(i)} feat_f8[j] — fp8 rows, 1 line/row -------
// 8 lane-groups x 8 lanes: group g owns neighbor-row k+g, lane loads uint4
// (16 fp8 values) at feat_f8[idx*128 + c*16]. One instruction = 8 rows =
// 8 lines (vs 8 lines for 4 rows in the bf16 form): line count HALVED,
// instruction count also halved. HW cvt_pk_f32_fp8 decode; fp32 accumulate;
// butterfly xor 8/16/32; lanes g==0 write bf16 agg (cols 16c..16c+15).
__global__ __launch_bounds__(256) void agg_kernel(
        const unsigned char* __restrict__ feat_f8,
        const int* __restrict__ deg,
        const unsigned short* __restrict__ bucket,
        bf16_t* __restrict__ agg) {
    int wid  = (blockIdx.x * 256 + threadIdx.x) >> 6;
    int lane = threadIdx.x & 63;
    if (wid >= N_NODES) return;
    int g = lane >> 3;         // neighbor-row group (0..7)
    int c = lane & 7;          // 16B chunk within the 128B fp8 row
    int d_true = deg[wid * DEG_PAD];
    int d = min(d_true, CAP);
    const unsigned short* row = bucket + (size_t)wid * CAP;   // 192B stride
    const uint4* yq = (const uint4*)feat_f8;   // row idx -> 8 uint4 chunks

    float acc[16];
#pragma unroll
    for (int i = 0; i < 16; ++i) acc[i] = 0.f;

#define ACC16(U) { \
    float2v f0 = fp8pair<false>((U).x), f1 = fp8pair<true>((U).x);  \
    float2v f2 = fp8pair<false>((U).y), f3 = fp8pair<true>((U).y);  \
    float2v f4 = fp8pair<false>((U).z), f5 = fp8pair<true>((U).z);  \
    float2v f6 = fp8pair<false>((U).w), f7 = fp8pair<true>((U).w);  \
    acc[0]+=f0.x; acc[1]+=f0.y; acc[2]+=f1.x; acc[3]+=f1.y;         \
    acc[4]+=f2.x; acc[5]+=f2.y; acc[6]+=f3.x; acc[7]+=f3.y;         \
    acc[8]+=f4.x; acc[9]+=f4.y; acc[10]+=f5.x; acc[11]+=f5.y;       \
    acc[12]+=f6.x; acc[13]+=f6.y; acc[14]+=f7.x; acc[15]+=f7.y; }

    int k = 0;
    for (; k + 32 <= d; k += 32) {            // 32 rows / 4 loads in flight
        int i0 = (int)row[k      + g];
        int i1 = (int)row[k + 8  + g];
        int i2 = (int)row[k + 16 + g];
        int i3 = (int)row[k + 24 + g];
        uint4 u0 = yq[i0 * 8 + c];
        uint4 u1 = yq[i1 * 8 + c];
        uint4 u2 = yq[i2 * 8 + c];
        uint4 u3 = yq[i3 * 8 + c];
        ACC16(u0); ACC16(u1); ACC16(u2); ACC16(u3);
    }
    for (; k + 8 <= d; k += 8) {              // 8 rows / 1 load
        int i0 = (int)row[k + g];
        uint4 u0 = yq[i0 * 8 + c];
        ACC16(u0);
    }
    if (k < d) {                              // predicated tail (<8 rows)
        int kk = k + g;
        int ia = (int)row[kk < d ? kk : (d - 1)];
        uint4 u = yq[ia * 8 + c];
        if (kk >= d) { u.x = 0u; u.y = 0u; u.z = 0u; u.w = 0u; }  // fp8 0x00 == 0.0
        ACC16(u);
    }
#undef ACC16

#pragma unroll
    for (int i = 0; i < 16; ++i) {
        acc[i] += __shfl_xor(acc[i], 8);
        acc[i] += __shfl_xor(acc[i], 16);
        acc[i] += __shfl_xor(acc[i], 32);
    }
    if (g == 0) {
        float inv = 1.0f / fmaxf((float)d_true, 1.0f);
        uint4 o1, o2;
        o1.x = (unsigned)f2bf(acc[0] * inv)  | ((unsigned)f2bf(acc[1] * inv)  << 16);
        o1.y = (unsigned)f2bf(acc[2] * inv)  | ((unsigned)f2bf(acc[3] * inv)  << 16);
        o1.z = (unsigned)f2bf(acc[4] * inv)  | ((unsigned)f2bf(acc[5] * inv)  << 16);
        o1.w = (unsigned)f2bf(acc[6] * inv)  | ((unsigned)f2bf(acc[7] * inv)  << 16);
        o2.x = (unsigned)f2bf(acc[8] * inv)  | ((unsigned)f2bf(acc[9] * inv)  << 16);
        o2.y = (unsigned)f2bf(acc[10] * inv) | ((unsigned)f2bf(acc[11] * inv) << 16);
        o2.z = (unsigned)f2bf(acc[12] * inv) | ((unsigned)f2bf(acc[13] * inv) << 16);
        o2.w = (unsigned)f2bf(acc[14] * inv) | ((unsigned)f2bf(acc[15] * inv) << 16);
        uint4* dst = (uint4*)(agg + (size_t)wid * HIDDEN + c * 16);
        dst[0] = o1;
        dst[1] = o2;
    }
}

// --- k3: MFMA GEMM  out = [agg | feat] @ [W_l ; W_r]^T + b  (fp32 out) -----
// (R2-verified form.) A-frag: lane holds A[m=lane&15][k=kt*32+(lane>>4)*8+j];
// kt<4 from agg, kt>=4 from feat_bf. C/D: col=lane&15, row=(lane>>4)*4+r
__global__ __launch_bounds__(256) void gemm_out_kernel(
        const bf16_t* __restrict__ agg,
        const bf16_t* __restrict__ feat_bf,
        const bf16_t* __restrict__ Bp,
        const float* __restrict__ bl,
        float* __restrict__ out) {
    int wid = blockIdx.x * 4 + (threadIdx.x >> 6);   // 16-row M-tile
    if (wid >= N_NODES / 16) return;
    int lane = threadIdx.x & 63;
    int m    = lane & 15;
    int quad = lane >> 4;
    int row0 = wid * 16;

    floatx4 acc[8];
    floatx4 zf = {0.f, 0.f, 0.f, 0.f};
#pragma unroll
    for (int nt = 0; nt < 8; ++nt) acc[nt] = zf;

    const short8* bp = (const short8*)Bp;
#pragma unroll
    for (int kt = 0; kt < 8; ++kt) {
        const bf16_t* abase = (kt < 4)
            ? (agg     + (size_t)(row0 + m) * HIDDEN + kt * 32 + quad * 8)
            : (feat_bf + (size_t)(row0 + m) * HIDDEN + (kt - 4) * 32 + quad * 8);
        short8 afrag = *(const short8*)abase;
#pragma unroll
        for (int nt = 0; nt < 8; ++nt) {
            short8 bfrag = bp[(kt * 8 + nt) * 64 + lane];
            acc[nt] = __builtin_amdgcn_mfma_f32_16x16x32_bf16(afrag, bfrag, acc[nt], 0, 0, 0);
        }
    }
    int col = lane & 15;
#pragma unroll
    for (int nt = 0; nt < 8; ++nt) {
        float b = bl[nt * 16 + col];
#pragma unroll
        for (int r = 0; r < 4; ++r) {
            int row = row0 + quad * 4 + r;
            out[(size_t)row * HIDDEN + nt * 16 + col] = acc[nt][r] + b;
        }
    }
}

extern "C" void kernel_launch(void* const* d_in, const int* in_sizes, int n_in,
                              void* d_out, int out_size, void* d_ws, size_t ws_size,
                              hipStream_t stream) {
    const float* feat = (const float*)d_in[0];
    const int*   eidx = (const int*)d_in[1];
    const float* Wl   = (const float*)d_in[2];
    const float* bl   = (const float*)d_in[3];
    const float* Wr   = (const float*)d_in[4];
    float* out = (float*)d_out;

    // workspace layout (~18 MB; ws is 256 MiB); all sections 16B-aligned
    int*            deg     = (int*)d_ws;                                   // 20000*16 int
    unsigned short* bucket  = (unsigned short*)(deg + N_NODES * DEG_PAD);   // 20000*96 u16
    bf16_t*         Bp      = (bf16_t*)(bucket + (size_t)N_NODES * CAP);    // 32768 bf16
    bf16_t*         feat_bf = Bp + 2 * HIDDEN * HIDDEN;                     // 20000*128 bf16
    bf16_t*         agg     = feat_bf + (size_t)N_NODES * HIDDEN;           // 20000*128 bf16
    unsigned char*  feat_f8 = (unsigned char*)(agg + (size_t)N_NODES * HIDDEN); // 20000*128 u8

    (void)hipMemsetAsync(deg, 0, (size_t)N_NODES * DEG_PAD * sizeof(int), stream);

    prep_fill_kernel<<<N_EDGES / 256, 256, 0, stream>>>(
        feat, Wl, Wr, eidx, feat_bf, feat_f8, Bp, deg, bucket);
    agg_kernel<<<(N_NODES * 64) / 256, 256, 0, stream>>>(
        feat_f8, deg, bucket, agg);
    gemm_out_kernel<<<(N_NODES / 16 + 3) / 4, 256, 0, stream>>>(
        agg, feat_bf, Bp, bl, out);
}

// Round 11
// 131.259 us; speedup vs baseline: 1.0572x; 1.0521x over previous
//
#include <hip/hip_runtime.h>

#define N_NODES 20000
#define N_EDGES 640000
#define HIDDEN  128
#define CAP     96        // max in-degree; Binomial(640K,1/20K) tail @96 ~ e^-45
#define DEG_PAD 16        // one counter per 64B line

typedef unsigned short bf16_t;
typedef __attribute__((ext_vector_type(8))) short short8;            // 8 bf16
typedef __attribute__((ext_vector_type(4))) float floatx4;            // MFMA C/D
typedef float float2v __attribute__((ext_vector_type(2)));

__device__ __forceinline__ bf16_t f2bf(float f) {
    union { float f; unsigned int i; } v; v.f = f;
    unsigned int x = v.i + 0x7FFFu + ((v.i >> 16) & 1u);   // RNE
    return (bf16_t)(x >> 16);
}
// float -> OCP e4m3fn, RNE, FTZ subnormals (values |f|<2^-6 -> 0; fine at our scale)
__device__ __forceinline__ unsigned f2fp8(float f) {
    union { float f; unsigned u; } v; v.f = f;
    unsigned s = (v.u >> 24) & 0x80u;
    unsigned a = v.u & 0x7FFFFFFFu;
    if (a > 0x43E00000u) a = 0x43E00000u;        // clamp to 448 (unreachable for N(0,1))
    a = a + 0x0007FFFFu + ((a >> 20) & 1u);      // RNE at 3-bit mantissa
    int e = (int)(a >> 23) - 120;
    unsigned m = (a >> 20) & 7u;
    unsigned em = (e <= 0) ? 0u : (((unsigned)e << 3) | m);
    if (e > 15) em = 0x7Eu;                      // clamp (unreachable)
    return s | em;
}
// 2x fp8(e4m3) -> 2x f32 from a dword; HI selects bytes 2,3. HW convert on
// gfx950; the builtin's word-select must be a LITERAL constant -> template.
template <bool HI>
__device__ __forceinline__ float2v fp8pair(unsigned w) {
#if defined(__has_builtin) && __has_builtin(__builtin_amdgcn_cvt_pk_f32_fp8)
    return __builtin_amdgcn_cvt_pk_f32_fp8(w, HI);
#else
    unsigned p = HI ? (w >> 16) : (w & 0xFFFFu);
    float2v r;
    {   unsigned b = p & 0xFFu, ss = (b & 0x80u) << 24, em = b & 0x7Fu;
        union { unsigned u; float f; } t; t.u = ss | ((em << 20) + 0x3C000000u);
        r.x = em ? t.f : 0.0f; }
    {   unsigned b = (p >> 8) & 0xFFu, ss = (b & 0x80u) << 24, em = b & 0x7Fu;
        union { unsigned u; float f; } t; t.u = ss | ((em << 20) + 0x3C000000u);
        r.y = em ? t.f : 0.0f; }
    return r;
#endif
}

// --- k1a: pure streaming — feat fp32 -> {bf16, fp8} + Bp weight pack -------
// No atomics, no scatter: should run at streaming BW (~4-6 us).
__global__ __launch_bounds__(256) void convert_kernel(
        const float* __restrict__ feat,
        const float* __restrict__ Wl,
        const float* __restrict__ Wr,
        bf16_t* __restrict__ feat_bf,
        unsigned char* __restrict__ feat_f8,
        bf16_t* __restrict__ Bp) {
    int t = blockIdx.x * 256 + threadIdx.x;    // 0 .. 639999 exactly
    float4 v = ((const float4*)feat)[t];
    ushort4 o = { f2bf(v.x), f2bf(v.y), f2bf(v.z), f2bf(v.w) };
    ((ushort4*)feat_bf)[t] = o;
    unsigned q = f2fp8(v.x) | (f2fp8(v.y) << 8) | (f2fp8(v.z) << 16) | (f2fp8(v.w) << 24);
    ((unsigned*)feat_f8)[t] = q;
    // Bp pack: 32768 entries (K=256 x N=128); layout per R2-verified form
    if (t < 2 * HIDDEN * HIDDEN) {
        int j    = t & 7;
        int lane = (t >> 3) & 63;
        int nt   = (t >> 9) & 7;
        int kt   = t >> 12;
        int n = nt * 16 + (lane & 15);
        int k = kt * 32 + (lane >> 4) * 8 + j;
        float w = (k < HIDDEN) ? Wl[n * HIDDEN + k] : Wr[n * HIDDEN + (k - HIDDEN)];
        Bp[t] = f2bf(w);
    }
}

// --- k1b: edge binning — 4 edges/lane, 4 independent atomic->store chains --
// The chain {atomicAdd (cross-XCD coherence round-trip) -> dependent 2B
// store} is the latency bind (R10: VALUBusy 2.4%, HBM 14%). 4 edges per
// lane via two coalesced int4 loads quadruples in-flight chains per lane.
__global__ __launch_bounds__(256) void fill_kernel(
        const int* __restrict__ eidx,
        int* __restrict__ deg,                 // pre-zeroed, stride DEG_PAD
        unsigned short* __restrict__ bucket) {
    int t = (blockIdx.x * 256 + threadIdx.x) * 4;   // 625 blocks: exact cover
    int4 s4 = *(const int4*)(eidx + t);
    int4 d4 = *(const int4*)(eidx + N_EDGES + t);
    int p0 = atomicAdd(&deg[d4.x * DEG_PAD], 1);
    int p1 = atomicAdd(&deg[d4.y * DEG_PAD], 1);
    int p2 = atomicAdd(&deg[d4.z * DEG_PAD], 1);
    int p3 = atomicAdd(&deg[d4.w * DEG_PAD], 1);
    if (p0 < CAP) bucket[d4.x * CAP + p0] = (unsigned short)s4.x;
    if (p1 < CAP) bucket[d4.y * CAP + p1] = (unsigned short)s4.y;
    if (p2 < CAP) bucket[d4.z * CAP + p2] = (unsigned short)s4.z;
    if (p3 < CAP) bucket[d4.w * CAP + p3] = (unsigned short)s4.w;
}

// --- k2: agg[i] = mean_{j in N(i)} feat_f8[j] — fp8 rows, 1 line/row -------
// (R10 form, verified: absmax unchanged at 0.03125.) 8 lane-groups x 8
// lanes; one uint4 load = 8 rows = 8 lines; HW cvt decode; butterfly reduce.
__global__ __launch_bounds__(256) void agg_kernel(
        const unsigned char* __restrict__ feat_f8,
        const int* __restrict__ deg,
        const unsigned short* __restrict__ bucket,
        bf16_t* __restrict__ agg) {
    int wid  = (blockIdx.x * 256 + threadIdx.x) >> 6;
    int lane = threadIdx.x & 63;
    if (wid >= N_NODES) return;
    int g = lane >> 3;         // neighbor-row group (0..7)
    int c = lane & 7;          // 16B chunk within the 128B fp8 row
    int d_true = deg[wid * DEG_PAD];
    int d = min(d_true, CAP);
    const unsigned short* row = bucket + (size_t)wid * CAP;   // 192B stride
    const uint4* yq = (const uint4*)feat_f8;   // row idx -> 8 uint4 chunks

    float acc[16];
#pragma unroll
    for (int i = 0; i < 16; ++i) acc[i] = 0.f;

#define ACC16(U) { \
    float2v f0 = fp8pair<false>((U).x), f1 = fp8pair<true>((U).x);  \
    float2v f2 = fp8pair<false>((U).y), f3 = fp8pair<true>((U).y);  \
    float2v f4 = fp8pair<false>((U).z), f5 = fp8pair<true>((U).z);  \
    float2v f6 = fp8pair<false>((U).w), f7 = fp8pair<true>((U).w);  \
    acc[0]+=f0.x; acc[1]+=f0.y; acc[2]+=f1.x; acc[3]+=f1.y;         \
    acc[4]+=f2.x; acc[5]+=f2.y; acc[6]+=f3.x; acc[7]+=f3.y;         \
    acc[8]+=f4.x; acc[9]+=f4.y; acc[10]+=f5.x; acc[11]+=f5.y;       \
    acc[12]+=f6.x; acc[13]+=f6.y; acc[14]+=f7.x; acc[15]+=f7.y; }

    int k = 0;
    for (; k + 32 <= d; k += 32) {            // 32 rows / 4 loads in flight
        int i0 = (int)row[k      + g];
        int i1 = (int)row[k + 8  + g];
        int i2 = (int)row[k + 16 + g];
        int i3 = (int)row[k + 24 + g];
        uint4 u0 = yq[i0 * 8 + c];
        uint4 u1 = yq[i1 * 8 + c];
        uint4 u2 = yq[i2 * 8 + c];
        uint4 u3 = yq[i3 * 8 + c];
        ACC16(u0); ACC16(u1); ACC16(u2); ACC16(u3);
    }
    for (; k + 8 <= d; k += 8) {              // 8 rows / 1 load
        int i0 = (int)row[k + g];
        uint4 u0 = yq[i0 * 8 + c];
        ACC16(u0);
    }
    if (k < d) {                              // predicated tail (<8 rows)
        int kk = k + g;
        int ia = (int)row[kk < d ? kk : (d - 1)];
        uint4 u = yq[ia * 8 + c];
        if (kk >= d) { u.x = 0u; u.y = 0u; u.z = 0u; u.w = 0u; }  // fp8 0x00 == 0.0
        ACC16(u);
    }
#undef ACC16

#pragma unroll
    for (int i = 0; i < 16; ++i) {
        acc[i] += __shfl_xor(acc[i], 8);
        acc[i] += __shfl_xor(acc[i], 16);
        acc[i] += __shfl_xor(acc[i], 32);
    }
    if (g == 0) {
        float inv = 1.0f / fmaxf((float)d_true, 1.0f);
        uint4 o1, o2;
        o1.x = (unsigned)f2bf(acc[0] * inv)  | ((unsigned)f2bf(acc[1] * inv)  << 16);
        o1.y = (unsigned)f2bf(acc[2] * inv)  | ((unsigned)f2bf(acc[3] * inv)  << 16);
        o1.z = (unsigned)f2bf(acc[4] * inv)  | ((unsigned)f2bf(acc[5] * inv)  << 16);
        o1.w = (unsigned)f2bf(acc[6] * inv)  | ((unsigned)f2bf(acc[7] * inv)  << 16);
        o2.x = (unsigned)f2bf(acc[8] * inv)  | ((unsigned)f2bf(acc[9] * inv)  << 16);
        o2.y = (unsigned)f2bf(acc[10] * inv) | ((unsigned)f2bf(acc[11] * inv) << 16);
        o2.z = (unsigned)f2bf(acc[12] * inv) | ((unsigned)f2bf(acc[13] * inv) << 16);
        o2.w = (unsigned)f2bf(acc[14] * inv) | ((unsigned)f2bf(acc[15] * inv) << 16);
        uint4* dst = (uint4*)(agg + (size_t)wid * HIDDEN + c * 16);
        dst[0] = o1;
        dst[1] = o2;
    }
}

// --- k3: MFMA GEMM  out = [agg | feat] @ [W_l ; W_r]^T + b  (fp32 out) -----
// (R2-verified form.) A-frag: lane holds A[m=lane&15][k=kt*32+(lane>>4)*8+j];
// kt<4 from agg, kt>=4 from feat_bf. C/D: col=lane&15, row=(lane>>4)*4+r
__global__ __launch_bounds__(256) void gemm_out_kernel(
        const bf16_t* __restrict__ agg,
        const bf16_t* __restrict__ feat_bf,
        const bf16_t* __restrict__ Bp,
        const float* __restrict__ bl,
        float* __restrict__ out) {
    int wid = blockIdx.x * 4 + (threadIdx.x >> 6);   // 16-row M-tile
    if (wid >= N_NODES / 16) return;
    int lane = threadIdx.x & 63;
    int m    = lane & 15;
    int quad = lane >> 4;
    int row0 = wid * 16;

    floatx4 acc[8];
    floatx4 zf = {0.f, 0.f, 0.f, 0.f};
#pragma unroll
    for (int nt = 0; nt < 8; ++nt) acc[nt] = zf;

    const short8* bp = (const short8*)Bp;
#pragma unroll
    for (int kt = 0; kt < 8; ++kt) {
        const bf16_t* abase = (kt < 4)
            ? (agg     + (size_t)(row0 + m) * HIDDEN + kt * 32 + quad * 8)
            : (feat_bf + (size_t)(row0 + m) * HIDDEN + (kt - 4) * 32 + quad * 8);
        short8 afrag = *(const short8*)abase;
#pragma unroll
        for (int nt = 0; nt < 8; ++nt) {
            short8 bfrag = bp[(kt * 8 + nt) * 64 + lane];
            acc[nt] = __builtin_amdgcn_mfma_f32_16x16x32_bf16(afrag, bfrag, acc[nt], 0, 0, 0);
        }
    }
    int col = lane & 15;
#pragma unroll
    for (int nt = 0; nt < 8; ++nt) {
        float b = bl[nt * 16 + col];
#pragma unroll
        for (int r = 0; r < 4; ++r) {
            int row = row0 + quad * 4 + r;
            out[(size_t)row * HIDDEN + nt * 16 + col] = acc[nt][r] + b;
        }
    }
}

extern "C" void kernel_launch(void* const* d_in, const int* in_sizes, int n_in,
                              void* d_out, int out_size, void* d_ws, size_t ws_size,
                              hipStream_t stream) {
    const float* feat = (const float*)d_in[0];
    const int*   eidx = (const int*)d_in[1];
    const float* Wl   = (const float*)d_in[2];
    const float* bl   = (const float*)d_in[3];
    const float* Wr   = (const float*)d_in[4];
    float* out = (float*)d_out;

    // workspace layout (~18 MB; ws is 256 MiB); all sections 16B-aligned
    int*            deg     = (int*)d_ws;                                   // 20000*16 int
    unsigned short* bucket  = (unsigned short*)(deg + N_NODES * DEG_PAD);   // 20000*96 u16
    bf16_t*         Bp      = (bf16_t*)(bucket + (size_t)N_NODES * CAP);    // 32768 bf16
    bf16_t*         feat_bf = Bp + 2 * HIDDEN * HIDDEN;                     // 20000*128 bf16
    bf16_t*         agg     = feat_bf + (size_t)N_NODES * HIDDEN;           // 20000*128 bf16
    unsigned char*  feat_f8 = (unsigned char*)(agg + (size_t)N_NODES * HIDDEN); // 20000*128 u8

    (void)hipMemsetAsync(deg, 0, (size_t)N_NODES * DEG_PAD * sizeof(int), stream);

    convert_kernel<<<N_EDGES / 256, 256, 0, stream>>>(
        feat, Wl, Wr, feat_bf, feat_f8, Bp);
    fill_kernel<<<N_EDGES / 1024, 256, 0, stream>>>(
        eidx, deg, bucket);
    agg_kernel<<<(N_NODES * 64) / 256, 256, 0, stream>>>(
        feat_f8, deg, bucket, agg);
    gemm_out_kernel<<<(N_NODES / 16 + 3) / 4, 256, 0, stream>>>(
        agg, feat_bf, Bp, bl, out);
}